// Round 7
// baseline (75.168 us; speedup 1.0000x reference)
//
#include <hip/hip_runtime.h>

#define BATCH 8192
#define IN 128
#define OUT 128
#define NB 18
#define ROW (IN * NB)            // 2304
#define CF_ELEMS (OUT * ROW)     // 294912

#define NPART 1024               // 256 m-tiles x 4 K-quarters
#define PART_OFF (1u << 20)                              // cfb2 @0 (590KB), part @1MB
#define XS_OFF   (PART_OFF + NPART * 4096u * 4u)         // + 16MB
#define WS_NEED  (XS_OFF + NPART * 32u * 4u)             // ~17.1MB

typedef short bf16x8 __attribute__((ext_vector_type(8)));
typedef float f32x16 __attribute__((ext_vector_type(16)));

static __device__ __forceinline__ unsigned short f2bf(float f) {
    union { float f; unsigned u; } v; v.f = f;
    unsigned r = v.u + 0x7fffu + ((v.u >> 16) & 1u);   // RNE
    return (unsigned short)(r >> 16);
}
static __device__ __forceinline__ bf16x8 as_bf16x8(uint4 v) {
    union { uint4 u; bf16x8 b; } x; x.u = v; return x.b;
}
static __device__ __forceinline__ float fast_tanh(float v) {
    float e = __expf(2.0f * v);
    return 1.0f - 2.0f * __builtin_amdgcn_rcpf(e + 1.0f);
}

// cf fp32 [o][k] -> cfb2 bf16 tiled [k>>3][o][k&7]
__global__ __launch_bounds__(256) void cvt_kernel(const float* __restrict__ cf,
                                                  unsigned short* __restrict__ cfb2) {
    int tid = blockIdx.x * 256 + threadIdx.x;
    int o  = tid & 127;
    int kb = tid >> 7;
    const float4* src = (const float4*)(cf + o * ROW + kb * 8);
    float4 a = src[0], b = src[1];
    uint4 pk;
    pk.x = (unsigned)f2bf(a.x) | ((unsigned)f2bf(a.y) << 16);
    pk.y = (unsigned)f2bf(a.z) | ((unsigned)f2bf(a.w) << 16);
    pk.z = (unsigned)f2bf(b.x) | ((unsigned)f2bf(b.y) << 16);
    pk.w = (unsigned)f2bf(b.z) | ((unsigned)f2bf(b.w) << 16);
    ((uint4*)cfb2)[tid] = pk;
}

// Block j: m-tile = j>>2 (32 batch rows), K-quarter = j&3 (2 chunks of 288).
// 4 waves = 4 N-slices of 32. Writes fp32 partial [32][128] + tanh partials.
__global__ __launch_bounds__(256, 4) void kan_part(const float* __restrict__ x,
                                                   const unsigned short* __restrict__ cfb2,
                                                   float* __restrict__ part,
                                                   float* __restrict__ xsums) {
    __shared__ unsigned sAT[36][128];   // 18.4 KB A-tile [k-granule][row*4+dw]
    __shared__ float sbuf[32][132];     // 16.9 KB x-stage (132%32=4 -> conflict-free)

    const int t  = threadIdx.x;
    const int j  = blockIdx.x;
    const int mg = j >> 2;
    const int kh = j & 3;
    const int b0 = mg << 5;
    const int wid = t >> 6;             // N-slice
    const int l  = t & 63;
    const int n0 = wid << 5;
    const int h  = l >> 5;              // k-octet half
    const int am = l & 31;
    const int ab = t >> 3;              // A-build row 0..31
    const int iq = t & 7;

    // ---- stage x[b0..b0+31][*] (coalesced float4; 132*4B = 33*16B aligned) ----
    {
        const float4* xp = (const float4*)(x + b0 * IN);
        #pragma unroll
        for (int q = 0; q < 4; ++q) {
            int i = t + (q << 8);
            *(float4*)&sbuf[i >> 5][(i & 31) << 2] = xp[i];
        }
    }

    f32x16 acc;
    #pragma unroll
    for (int r = 0; r < 16; ++r) acc[r] = 0.f;
    float xs = 0.f;
    const uint4* bbase = (const uint4*)cfb2;

    #pragma unroll
    for (int cc = 0; cc < 2; ++cc) {
        const int c = (kh << 1) + cc;   // chunk index 0..7
        __syncthreads();                // x-stage done (cc=0) / prior A-reads done (cc=1)

        // ---- build A-tile: 2 cells (b=ab, i=16c+iq, +8), 18 cols each ----
        #pragma unroll
        for (int hh = 0; hh < 2; ++hh) {
            int il = iq + (hh << 3);
            int i  = (c << 4) + il;
            float xt = fast_tanh(sbuf[ab][i]);
            xs += xt;
            float s = (xt + 1.0f) * 7.5f;       // (xt+1)/h, h=2/15
            int m = (int)s; m = m < 0 ? 0 : (m > 14 ? 14 : m);
            float u = s - (float)m, om = 1.f - u, u2 = u * u;
            float w0 = (1.f / 6.f) * om * om * om;
            float w1 = (2.f / 3.f) - u2 * (1.f - 0.5f * u);
            float w2 = (1.f / 6.f) + 0.5f * (u + u2 - u2 * u);
            float w3 = (1.f / 6.f) * u * u2;
            unsigned lo = (unsigned)f2bf(w0) | ((unsigned)f2bf(w1) << 16);
            unsigned hi = (unsigned)f2bf(w2) | ((unsigned)f2bf(w3) << 16);
            int odd = m & 1;
            unsigned t0 = odd ? (lo << 16) : lo;
            unsigned t1 = odd ? ((hi << 16) | (lo >> 16)) : hi;
            unsigned t2 = odd ? (hi >> 16) : 0u;
            int dq = m >> 1;
            int d0 = il * 9;
            #pragma unroll
            for (int jj = 0; jj < 9; ++jj) {
                int d = d0 + jj;
                unsigned v = (jj == dq) ? t0 : (jj == dq + 1) ? t1
                           : (jj == dq + 2) ? t2 : 0u;
                sAT[d >> 2][(ab << 2) + (d & 3)] = v;    // 2-way max (free)
            }
        }
        __syncthreads();

        // ---- 18 MFMA steps; A: contiguous 512B half-wave ds_read_b128 ----
        #pragma unroll
        for (int s = 0; s < 18; ++s) {
            uint4 bv = bbase[(c * 36 + 2 * s + h) * 128 + n0 + am];
            uint4 av = *(const uint4*)(&sAT[0][0] + (((2 * s + h) << 7) + (am << 2)));
            acc = __builtin_amdgcn_mfma_f32_32x32x16_bf16(
                      as_bf16x8(av), as_bf16x8(bv), acc, 0, 0, 0);
        }
    }

    // ---- tanh partial sums: 8 consecutive lanes share ab ----
    xs += __shfl_down(xs, 4, 8);
    xs += __shfl_down(xs, 2, 8);
    xs += __shfl_down(xs, 1, 8);
    if (iq == 0) xsums[(j << 5) + ab] = xs;

    // ---- store fp32 partial tile (C/D layout col=l&31, row=(r&3)+8*(r>>2)+4*h) ----
    float* pj = part + (j << 12);
    #pragma unroll
    for (int r = 0; r < 16; ++r) {
        int row = (r & 3) + ((r >> 2) << 3) + (h << 2);
        pj[row * OUT + n0 + am] = acc[r];
    }
}

// out[b][o] = (sum_kh part + sum_kh xs[b]) / 128, fully coalesced float4
__global__ __launch_bounds__(256) void kan_fin(const float* __restrict__ part,
                                               const float* __restrict__ xsums,
                                               float* __restrict__ out) {
    int t0 = blockIdx.x * 256 + threadIdx.x;
    const float4* p4 = (const float4*)part;
    float4* o4 = (float4*)out;
    #pragma unroll
    for (int q = 0; q < 4; ++q) {
        int v   = t0 + (q << 16);       // float4 index into [8192][128]
        int b   = v >> 5;
        int o   = v & 31;
        int jb  = (b >> 5) << 2;        // first of 4 K-quarter blocks for this m-tile
        int l32 = b & 31;
        int base = (l32 << 5) + o;
        float4 a = p4[(jb + 0) * 1024 + base];
        float4 bb = p4[(jb + 1) * 1024 + base];
        float4 cS = p4[(jb + 2) * 1024 + base];
        float4 d = p4[(jb + 3) * 1024 + base];
        float xsv = xsums[(jb + 0) * 32 + l32] + xsums[(jb + 1) * 32 + l32]
                  + xsums[(jb + 2) * 32 + l32] + xsums[(jb + 3) * 32 + l32];
        float4 r;
        r.x = (a.x + bb.x + cS.x + d.x + xsv) * (1.0f / 128.0f);
        r.y = (a.y + bb.y + cS.y + d.y + xsv) * (1.0f / 128.0f);
        r.z = (a.z + bb.z + cS.z + d.z + xsv) * (1.0f / 128.0f);
        r.w = (a.w + bb.w + cS.w + d.w + xsv) * (1.0f / 128.0f);
        o4[v] = r;
    }
}

// ---------------- fallback (ws too small): R3's proven VALU kernel ----------------
__global__ __launch_bounds__(256, 2) void kan_valu(const float* __restrict__ x,
                                                   const float* __restrict__ cf,
                                                   float* __restrict__ out) {
    __shared__ float4        s_w[16][IN];
    __shared__ unsigned char s_m[16][IN];
    __shared__ float         s_xs[16];
    const int t = threadIdx.x;
    const int boff = blockIdx.x * 16;
    {
        const int b = t >> 4, il = t & 15;
        float xs = 0.f;
        #pragma unroll
        for (int k = 0; k < IN / 16; ++k) {
            int i = il + 16 * k;
            float xt = tanhf(x[(boff + b) * IN + i]);
            xs += xt;
            float s = (xt + 1.0f) * 7.5f;
            int m = (int)s; m = m < 0 ? 0 : (m > 14 ? 14 : m);
            float u = s - (float)m, om = 1.f - u, u2 = u * u;
            s_w[b][i] = make_float4((1.f/6.f)*om*om*om,
                                    (2.f/3.f) - u2*(1.f - 0.5f*u),
                                    (1.f/6.f) + 0.5f*(u + u2 - u2*u),
                                    (1.f/6.f)*u*u2);
            s_m[b][i] = (unsigned char)m;
        }
        for (int d = 8; d > 0; d >>= 1) xs += __shfl_down(xs, d, 16);
        if (il == 0) s_xs[b] = xs;
    }
    __syncthreads();
    const int w = t >> 6, l = t & 63;
    #pragma unroll
    for (int r = 0; r < 4; ++r) {
        const int b = w * 4 + r;
        float a0 = 0.f, a1 = 0.f;
        for (int i = 0; i < IN; ++i) {
            float4 wv = s_w[b][i];
            int m = (int)s_m[b][i];
            const float* p0 = cf + (2 * l) * ROW + i * NB + m;
            const float* p1 = p0 + ROW;
            a0 += wv.x * p0[0] + wv.y * p0[1] + wv.z * p0[2] + wv.w * p0[3];
            a1 += wv.x * p1[0] + wv.y * p1[1] + wv.z * p1[2] + wv.w * p1[3];
        }
        float xsv = s_xs[b];
        float2 st; st.x = (xsv + a0) / 128.f; st.y = (xsv + a1) / 128.f;
        ((float2*)out)[(boff + b) * (OUT / 2) + l] = st;
    }
}

extern "C" void kernel_launch(void* const* d_in, const int* in_sizes, int n_in,
                              void* d_out, int out_size, void* d_ws, size_t ws_size,
                              hipStream_t stream) {
    const float* x  = (const float*)d_in[0];
    const float* cf = (const float*)d_in[1];
    float* out = (float*)d_out;
    if (ws_size >= (size_t)WS_NEED) {
        unsigned short* cfb2 = (unsigned short*)d_ws;
        float* part  = (float*)((char*)d_ws + PART_OFF);
        float* xsums = (float*)((char*)d_ws + XS_OFF);
        cvt_kernel<<<CF_ELEMS / 8 / 256, 256, 0, stream>>>(cf, cfb2);
        kan_part<<<NPART, 256, 0, stream>>>(x, cfb2, part, xsums);
        kan_fin<<<256, 256, 0, stream>>>(part, xsums, out);
    } else {
        kan_valu<<<BATCH / 16, 256, 0, stream>>>(x, cf, out);
    }
}

// Round 8
// 70.320 us; speedup vs baseline: 1.0689x; 1.0689x over previous
//
#include <hip/hip_runtime.h>

#define BATCH 8192
#define IN 128
#define OUT 128
#define NB 18
#define ROW (IN * NB)            // 2304
#define CF_ELEMS (OUT * ROW)     // 294912
#define WS_NEED (CF_ELEMS * 2u)  // 590 KB bf16 copy of cf

typedef short bf16x8 __attribute__((ext_vector_type(8)));
typedef float f32x16 __attribute__((ext_vector_type(16)));

static __device__ __forceinline__ unsigned short f2bf(float f) {
    union { float f; unsigned u; } v; v.f = f;
    unsigned r = v.u + 0x7fffu + ((v.u >> 16) & 1u);   // RNE
    return (unsigned short)(r >> 16);
}
static __device__ __forceinline__ bf16x8 as_bf16x8(uint4 v) {
    union { uint4 u; bf16x8 b; } x; x.u = v; return x.b;
}
static __device__ __forceinline__ float fast_tanh(float v) {
    float e = __expf(2.0f * v);
    return 1.0f - 2.0f * __builtin_amdgcn_rcpf(e + 1.0f);
}

// cf fp32 [o][k] -> cfb2 bf16 tiled [k>>3][o][k&7]
__global__ __launch_bounds__(256) void cvt_kernel(const float* __restrict__ cf,
                                                  unsigned short* __restrict__ cfb2) {
    int tid = blockIdx.x * 256 + threadIdx.x;
    int o  = tid & 127;
    int kb = tid >> 7;
    const float4* src = (const float4*)(cf + o * ROW + kb * 8);
    float4 a = src[0], b = src[1];
    uint4 pk;
    pk.x = (unsigned)f2bf(a.x) | ((unsigned)f2bf(a.y) << 16);
    pk.y = (unsigned)f2bf(a.z) | ((unsigned)f2bf(a.w) << 16);
    pk.z = (unsigned)f2bf(b.x) | ((unsigned)f2bf(b.y) << 16);
    pk.w = (unsigned)f2bf(b.z) | ((unsigned)f2bf(b.w) << 16);
    ((uint4*)cfb2)[tid] = pk;
}

// 256 blocks (1 m-tile of 32 rows each), 512 thr, 2 blocks/CU.
// Waves 0-3 = K-group 0 (i 0..63), waves 4-7 = K-group 1 (i 64..127);
// within a group, 4 waves = 4 N-slices. Intra-block K-reduction via LDS.
__global__ __launch_bounds__(512, 4) void kan_mfma(const float* __restrict__ x,
                                                   const unsigned short* __restrict__ cfb2,
                                                   float* __restrict__ out) {
    __shared__ unsigned sAT[2][36][128];   // 36.9 KB: per-group A [k-granule][row*4+dw]
    __shared__ float sbuf[32][132];        // 16.9 KB: x-stage, then C-reduction
    __shared__ float s_xsp[2][32];

    const int t  = threadIdx.x;
    const int g  = t >> 8;          // K-group
    const int tg = t & 255;
    const int w4 = (t >> 6) & 3;    // N-slice
    const int l  = t & 63;
    const int b0 = blockIdx.x << 5;
    const int n0 = w4 << 5;
    const int ab = tg >> 3;         // A-build row 0..31
    const int iq = tg & 7;
    const int h  = l >> 5;          // k-octet half
    const int am = l & 31;

    // ---- stage x[b0..b0+31][*] (coalesced float4; 132 dw = 33*16B aligned) ----
    {
        const float4* xp = (const float4*)(x + b0 * IN);
        int i0 = t;
        *(float4*)&sbuf[i0 >> 5][(i0 & 31) << 2] = xp[i0];
        int i1 = t + 512;
        *(float4*)&sbuf[i1 >> 5][(i1 & 31) << 2] = xp[i1];
    }

    f32x16 acc;
    #pragma unroll
    for (int r = 0; r < 16; ++r) acc[r] = 0.f;
    float xs = 0.f;
    const uint4* bbase = (const uint4*)cfb2;

    #pragma unroll
    for (int cc = 0; cc < 4; ++cc) {
        const int c = (g << 2) + cc;    // chunk 0..7 (288 k each)
        __syncthreads();                // x-stage (cc=0) / prior A-reads done

        // ---- build A-tile: 2 cells (b=ab, i=16c+iq, +8); zeros then taps ----
        unsigned* tile = &sAT[g][0][0];
        #pragma unroll
        for (int hh = 0; hh < 2; ++hh) {
            int il = iq + (hh << 3);
            int i  = (c << 4) + il;
            float xt = fast_tanh(sbuf[ab][i]);
            xs += xt;
            float s = (xt + 1.0f) * 7.5f;       // (xt+1)/h, h=2/15
            int m = (int)s; m = m < 0 ? 0 : (m > 14 ? 14 : m);
            float u = s - (float)m, om = 1.f - u, u2 = u * u;
            float w0 = (1.f / 6.f) * om * om * om;
            float w1 = (2.f / 3.f) - u2 * (1.f - 0.5f * u);
            float w2 = (1.f / 6.f) + 0.5f * (u + u2 - u2 * u);
            float w3 = (1.f / 6.f) * u * u2;
            unsigned lo = (unsigned)f2bf(w0) | ((unsigned)f2bf(w1) << 16);
            unsigned hi = (unsigned)f2bf(w2) | ((unsigned)f2bf(w3) << 16);
            int odd = m & 1;
            unsigned t0 = odd ? (lo << 16) : lo;
            unsigned t1 = odd ? ((hi << 16) | (lo >> 16)) : hi;
            unsigned t2 = odd ? (hi >> 16) : 0u;
            int dq = m >> 1;                    // 0..7
            int d0 = il * 9;
            // zero the 9-dword cell (granule layout: addr = (d>>2)*128 + ab*4 + (d&3))
            #pragma unroll
            for (int jj = 0; jj < 9; ++jj) {
                int d = d0 + jj;
                tile[((d >> 2) << 7) + (ab << 2) + (d & 3)] = 0u;
            }
            // taps at dq, dq+1, dq+2. When m even, dq may be 7 -> dq+2=9 would
            // leave the cell; t2==0 there, so clamp to 8 and write t2 BEFORE t1.
            int d2 = d0 + (dq + 2 > 8 ? 8 : dq + 2);
            tile[((d2 >> 2) << 7) + (ab << 2) + (d2 & 3)] = t2;
            int d1 = d0 + dq + 1;
            tile[((d1 >> 2) << 7) + (ab << 2) + (d1 & 3)] = t1;
            int dd = d0 + dq;
            tile[((dd >> 2) << 7) + (ab << 2) + (dd & 3)] = t0;
        }
        __syncthreads();

        // ---- 18 MFMA steps; rolling 6-deep B prefetch (24 VGPRs) ----
        const int boct = c * 36 + h;    // this lane's first octet of the chunk
        uint4 Bq[6];
        #pragma unroll
        for (int p = 0; p < 6; ++p)
            Bq[p] = bbase[(boct + 2 * p) * 128 + n0 + am];
        #pragma unroll
        for (int s = 0; s < 18; ++s) {
            uint4 bv = Bq[s % 6];
            if (s + 6 < 18)
                Bq[s % 6] = bbase[(boct + 2 * (s + 6)) * 128 + n0 + am];
            uint4 av = *(const uint4*)(&sAT[g][0][0] + (((2 * s + h) << 7) + (am << 2)));
            acc = __builtin_amdgcn_mfma_f32_32x32x16_bf16(
                      as_bf16x8(av), as_bf16x8(bv), acc, 0, 0, 0);
        }
    }

    // ---- tanh partial sums: 8 consecutive lanes share (g, ab) ----
    xs += __shfl_down(xs, 4, 8);
    xs += __shfl_down(xs, 2, 8);
    xs += __shfl_down(xs, 1, 8);
    if (iq == 0) s_xsp[g][ab] = xs;

    // ---- K-group reduction via sbuf (x-stage dead after last build+barrier) ----
    if (g == 1) {
        #pragma unroll
        for (int r = 0; r < 16; ++r) {
            int row = (r & 3) + ((r >> 2) << 3) + (h << 2);
            sbuf[row][n0 + am] = acc[r];
        }
    }
    __syncthreads();
    if (g == 0) {
        #pragma unroll
        for (int r = 0; r < 16; ++r) {
            int row = (r & 3) + ((r >> 2) << 3) + (h << 2);
            float v = acc[r] + sbuf[row][n0 + am] + s_xsp[0][row] + s_xsp[1][row];
            out[(b0 + row) * OUT + n0 + am] = v * (1.0f / 128.0f);
        }
    }
}

// ---------------- fallback (ws too small): R3's proven VALU kernel ----------------
__global__ __launch_bounds__(256, 2) void kan_valu(const float* __restrict__ x,
                                                   const float* __restrict__ cf,
                                                   float* __restrict__ out) {
    __shared__ float4        s_w[16][IN];
    __shared__ unsigned char s_m[16][IN];
    __shared__ float         s_xs[16];
    const int t = threadIdx.x;
    const int boff = blockIdx.x * 16;
    {
        const int b = t >> 4, il = t & 15;
        float xs = 0.f;
        #pragma unroll
        for (int k = 0; k < IN / 16; ++k) {
            int i = il + 16 * k;
            float xt = tanhf(x[(boff + b) * IN + i]);
            xs += xt;
            float s = (xt + 1.0f) * 7.5f;
            int m = (int)s; m = m < 0 ? 0 : (m > 14 ? 14 : m);
            float u = s - (float)m, om = 1.f - u, u2 = u * u;
            s_w[b][i] = make_float4((1.f/6.f)*om*om*om,
                                    (2.f/3.f) - u2*(1.f - 0.5f*u),
                                    (1.f/6.f) + 0.5f*(u + u2 - u2*u),
                                    (1.f/6.f)*u*u2);
            s_m[b][i] = (unsigned char)m;
        }
        for (int d = 8; d > 0; d >>= 1) xs += __shfl_down(xs, d, 16);
        if (il == 0) s_xs[b] = xs;
    }
    __syncthreads();
    const int w = t >> 6, l = t & 63;
    #pragma unroll
    for (int r = 0; r < 4; ++r) {
        const int b = w * 4 + r;
        float a0 = 0.f, a1 = 0.f;
        for (int i = 0; i < IN; ++i) {
            float4 wv = s_w[b][i];
            int m = (int)s_m[b][i];
            const float* p0 = cf + (2 * l) * ROW + i * NB + m;
            const float* p1 = p0 + ROW;
            a0 += wv.x * p0[0] + wv.y * p0[1] + wv.z * p0[2] + wv.w * p0[3];
            a1 += wv.x * p1[0] + wv.y * p1[1] + wv.z * p1[2] + wv.w * p1[3];
        }
        float xsv = s_xs[b];
        float2 st; st.x = (xsv + a0) / 128.f; st.y = (xsv + a1) / 128.f;
        ((float2*)out)[(boff + b) * (OUT / 2) + l] = st;
    }
}

extern "C" void kernel_launch(void* const* d_in, const int* in_sizes, int n_in,
                              void* d_out, int out_size, void* d_ws, size_t ws_size,
                              hipStream_t stream) {
    const float* x  = (const float*)d_in[0];
    const float* cf = (const float*)d_in[1];
    float* out = (float*)d_out;
    if (ws_size >= (size_t)WS_NEED) {
        unsigned short* cfb2 = (unsigned short*)d_ws;
        cvt_kernel<<<CF_ELEMS / 8 / 256, 256, 0, stream>>>(cf, cfb2);
        kan_mfma<<<BATCH / 32, 512, 0, stream>>>(x, cfb2, out);
    } else {
        kan_valu<<<BATCH / 16, 256, 0, stream>>>(x, cf, out);
    }
}